// Round 19
// baseline (470.370 us; speedup 1.0000x reference)
//
#include <hip/hip_runtime.h>
#include <hip/hip_bf16.h>
#include <math.h>

#define NN 25000
#define NE 400000
#define HH 128
#define NH (NN*HH)
#define NBINS 2048

#define GS_STEP  (8.0f/15.0f)
#define GS_COEFF (-1.7578125f)
#define LOG2E    1.442695041f
#define LN2      0.6931471806f
#define BINSC    ((float)NBINS / 8.0f)

typedef float f32x2 __attribute__((ext_vector_type(2)));
typedef float f32x4 __attribute__((ext_vector_type(4)));
typedef short bf16x8 __attribute__((ext_vector_type(8)));

__device__ __forceinline__ f32x2 bf2_unpack(unsigned int u) {
  union { unsigned int i; float f; } lo, hi;
  lo.i = u << 16;
  hi.i = u & 0xffff0000u;
  f32x2 r; r.x = lo.f; r.y = hi.f;
  return r;
}

__device__ __forceinline__ unsigned short bf16_of(float f) {
  return __hip_bfloat16_raw(__float2bfloat16(f)).x;
}

// --- fused prep: weight pack + bf16 LUT + stats zero + (plane y==2) hist ---
__global__ __launch_bounds__(256) void k_prep(
    const float* __restrict__ f1w, const float* __restrict__ s1w,
    const float* __restrict__ f1b, const float* __restrict__ s1b,
    const float* __restrict__ f2w, const float* __restrict__ s2w,
    const float* __restrict__ f2b, const float* __restrict__ s2b,
    unsigned short* __restrict__ Wf1, float* __restrict__ bv1,
    unsigned short* __restrict__ L1,
    unsigned short* __restrict__ Wf2, float* __restrict__ bv2,
    unsigned short* __restrict__ L2, float* __restrict__ statsall,
    int* __restrict__ deg, const int* __restrict__ ei,
    int* __restrict__ rank) {
  const int bx = blockIdx.x;
  const int tid = threadIdx.x;
  if (blockIdx.y == 2) {   // hist plane: count degrees + record ranks
    int e = bx * 256 + tid;
    if (e < NE) rank[e] = atomicAdd(&deg[ei[NE + e]], 1);
    return;
  }
  if (bx >= 1281) return;  // prep planes use x < 1281 only
  const int layer = blockIdx.y;
  const float* fw = layer ? f2w : f1w;
  const float* sw = layer ? s2w : s1w;
  const float* fb = layer ? f2b : f1b;
  const float* sb = layer ? s2b : s1b;
  unsigned short* Wf = layer ? Wf2 : Wf1;
  float* biasv = layer ? bv2 : bv1;
  unsigned short* LUT = layer ? L2 : L1;
  if (bx < 256) {
    if (bx == 0) statsall[layer * 256 + tid] = 0.f;
    const int t = bx * 256 + tid;
    if (t < 512) biasv[t] = (t < 256) ? ((t & 1) ? sb[t >> 1] : fb[t >> 1]) : 0.f;
    const int j = t & 7;
    const int lane = (t >> 3) & 63;
    const int kt = (t >> 9) & 3;
    const int nt = t >> 11;
    const int k = 32 * kt + 8 * (lane >> 4) + j;
    const int c = 16 * nt + (lane & 15);
    const int cc = c & 255;
    const int row = ((c >= 256) ? 128 : 0) + k;
    const float* m = (cc & 1) ? sw : fw;
    Wf[t] = bf16_of(m[row * HH + (cc >> 1)]);
  } else {
    const int bin = (bx - 256) * 2 + (tid >> 7);
    if (bin > NBINS) return;
    const int j = tid & 127;
    const float* fw3 = fw + 256 * HH;
    const float* sw3 = sw + 256 * HH;
    const float d = (float)bin * (8.0f / (float)NBINS);
    f32x2 acc = 0.f;
#pragma unroll
    for (int k = 0; k < 16; ++k) {
      float tt = d - (float)k * GS_STEP;
      float ee = __expf(GS_COEFF * tt * tt);
      f32x2 w;
      w.x = fw3[k * HH + j];
      w.y = sw3[k * HH + j];
      acc = __builtin_elementwise_fma((f32x2)(ee), w, acc);
    }
    *(unsigned int*)&LUT[bin * 256 + 2 * j] =
        (unsigned int)bf16_of(acc.x) | ((unsigned int)bf16_of(acc.y) << 16);
  }
}

// ============ shared MFMA core: 128x128 tile, 4 waves; bf16 PD+PS ==========
__device__ __forceinline__ void gemm_core(
    const unsigned short* As, const unsigned short* __restrict__ Wfrag,
    const float* __restrict__ biasv, int n0, int bn0,
    unsigned short* __restrict__ PDh, unsigned short* __restrict__ PSh,
    int tid) {
  const int w = tid >> 6;
  const int lane = tid & 63;
  const int mt0 = 2 * w;
  f32x4 acc[2][8];
#pragma unroll
  for (int mi = 0; mi < 2; ++mi)
#pragma unroll
    for (int nt = 0; nt < 8; ++nt) acc[mi][nt] = (f32x4)0.f;
  const int ntg0 = bn0 >> 4;
#pragma unroll
  for (int kt = 0; kt < 4; ++kt) {
    const bf16x8 a0 = *(const bf16x8*)&As[((mt0 * 4 + kt) * 64 + lane) * 8];
    const bf16x8 a1 = *(const bf16x8*)&As[(((mt0 + 1) * 4 + kt) * 64 + lane) * 8];
#pragma unroll
    for (int nt = 0; nt < 8; ++nt) {
      const bf16x8 b =
          *(const bf16x8*)&Wfrag[(((ntg0 + nt) * 4 + kt) * 64 + lane) * 8];
      acc[0][nt] = __builtin_amdgcn_mfma_f32_16x16x32_bf16(a0, b, acc[0][nt], 0, 0, 0);
      acc[1][nt] = __builtin_amdgcn_mfma_f32_16x16x32_bf16(a1, b, acc[1][nt], 0, 0, 0);
    }
  }
  const int colloc = lane & 15;
  const int rbase = (lane >> 4) * 4;
  const bool isPD = (bn0 < 256);
#pragma unroll
  for (int mi = 0; mi < 2; ++mi) {
#pragma unroll
    for (int nt = 0; nt < 8; ++nt) {
      const int c = bn0 + nt * 16 + colloc;
      const float bias = biasv[c];
#pragma unroll
      for (int r = 0; r < 4; ++r) {
        const int n = n0 + (mt0 + mi) * 16 + rbase + r;
        if (n < NN) {
          const float vv = acc[mi][nt][r] + bias;
          if (isPD) PDh[n * 256 + c] = bf16_of(vv);
          else PSh[n * 256 + (c - 256)] = bf16_of(vv);
        }
      }
    }
  }
}

// ---------------- layer-1 GEMM: fused node-embed staging + bufB zeroing ----
__global__ __launch_bounds__(256) void k_gemm1(
    const float* __restrict__ x, const float* __restrict__ nw,
    const float* __restrict__ nb, const unsigned short* __restrict__ Wfrag,
    const float* __restrict__ biasv, float* __restrict__ h0,
    unsigned short* __restrict__ PDh, unsigned short* __restrict__ PSh,
    float* __restrict__ zb) {
  __shared__ unsigned short As[128 * 128];
  __shared__ float wn[6 * 128 + 128];
  const int tid = threadIdx.x;
  const int n0 = blockIdx.x * 128;
  const int bn0 = blockIdx.y * 128;
  const bool wr_h0 = (blockIdx.y == 0);
  for (int i = tid; i < 6 * 128 + 128; i += 256)
    wn[i] = (i < 6 * 128) ? nw[i] : nb[i - 6 * 128];
  if (blockIdx.y == 1) {
    const float4 z = {0.f, 0.f, 0.f, 0.f};
    for (int i = tid; i < 128 * 32; i += 256) {
      const int n = n0 + (i >> 5);
      if (n < NN) *(float4*)&zb[n * HH + (i & 31) * 4] = z;
    }
  }
  __syncthreads();
  {
    const int tn = tid >> 2;
    const int cj = tid & 3;
#pragma unroll
    for (int ii = 0; ii < 2; ++ii) {
      const int n = tn + 64 * ii;
      const int gn = n0 + n;
      float xr[6];
      if (gn < NN) {
#pragma unroll
        for (int q = 0; q < 6; ++q) xr[q] = x[gn * 6 + q];
      }
#pragma unroll
      for (int i = 0; i < 4; ++i) {
        const int c = cj + 4 * i;
        bf16x8 bv = (bf16x8)0;
        if (gn < NN) {
          float4 r0, r1;
#pragma unroll
          for (int j = 0; j < 8; ++j) {
            const int k = c * 8 + j;
            float acc = wn[6 * 128 + k];
#pragma unroll
            for (int q = 0; q < 6; ++q) acc = fmaf(xr[q], wn[q * 128 + k], acc);
            if (j < 4) (&r0.x)[j] = acc; else (&r1.x)[j - 4] = acc;
            bv[j] = (short)bf16_of(acc);
          }
          if (wr_h0) {
            *(float4*)&h0[gn * HH + c * 8] = r0;
            *(float4*)&h0[gn * HH + c * 8 + 4] = r1;
          }
        }
        const int slot = ((n >> 4) * 4 + (c >> 2)) * 64 + (n & 15) + 16 * (c & 3);
        *(bf16x8*)&As[slot * 8] = bv;
      }
    }
  }
  __syncthreads();
  gemm_core(As, Wfrag, biasv, n0, bn0, PDh, PSh, tid);
}

// ---------------- layer-2 GEMM: plain h input ------------------------------
__global__ __launch_bounds__(256) void k_gemm_mfma(
    const float* __restrict__ h, const unsigned short* __restrict__ Wfrag,
    const float* __restrict__ biasv,
    unsigned short* __restrict__ PDh, unsigned short* __restrict__ PSh) {
  __shared__ unsigned short As[128 * 128];
  const int tid = threadIdx.x;
  const int n0 = blockIdx.x * 128;
  const int bn0 = blockIdx.y * 128;
  {
    const int tn = tid >> 2;
    const int cj = tid & 3;
#pragma unroll
    for (int ii = 0; ii < 2; ++ii) {
      const int n = tn + 64 * ii;
      const int gn = n0 + n;
#pragma unroll
      for (int i = 0; i < 4; ++i) {
        const int c = cj + 4 * i;
        bf16x8 bv;
        if (gn < NN) {
          const float4 p0 = *(const float4*)&h[gn * HH + c * 8];
          const float4 p1 = *(const float4*)&h[gn * HH + c * 8 + 4];
          bv[0] = (short)bf16_of(p0.x); bv[1] = (short)bf16_of(p0.y);
          bv[2] = (short)bf16_of(p0.z); bv[3] = (short)bf16_of(p0.w);
          bv[4] = (short)bf16_of(p1.x); bv[5] = (short)bf16_of(p1.y);
          bv[6] = (short)bf16_of(p1.z); bv[7] = (short)bf16_of(p1.w);
        } else {
          bv = (bf16x8)0;
        }
        const int slot = ((n >> 4) * 4 + (c >> 2)) * 64 + (n & 15) + 16 * (c & 3);
        *(bf16x8*)&As[slot * 8] = bv;
      }
    }
  }
  __syncthreads();
  gemm_core(As, Wfrag, biasv, n0, bn0, PDh, PSh, tid);
}

__global__ __launch_bounds__(1024) void k_scan(
    const int* __restrict__ deg, int* __restrict__ rowptr) {
  __shared__ int part[1024];
  const int tid = threadIdx.x;
  const int CH = (NN + 1023) / 1024;
  const int base = tid * CH;
  int s = 0;
  for (int i = 0; i < CH; ++i) {
    int n = base + i;
    if (n < NN) s += deg[n];
  }
  part[tid] = s;
  __syncthreads();
  for (int off = 1; off < 1024; off <<= 1) {
    int t = (tid >= off) ? part[tid - off] : 0;
    __syncthreads();
    part[tid] += t;
    __syncthreads();
  }
  int run = part[tid] - s;
  for (int i = 0; i < CH; ++i) {
    int n = base + i;
    if (n < NN) {
      rowptr[n] = run;
      run += deg[n];
    }
  }
}

// scatter: atomic-free; pos = rowptr[dst] + rank[e]; 8B packed metadata
__global__ __launch_bounds__(256) void k_scatter(
    const int* __restrict__ ei, const float* __restrict__ eattr,
    const int* __restrict__ rowptr, const int* __restrict__ rank,
    int2* __restrict__ emeta) {
  int e = blockIdx.x * 256 + threadIdx.x;
  if (e >= NE) return;
  const int dst = ei[NE + e];
  const int src = ei[e];
  const int bin = (int)(eattr[e] * BINSC + 0.5f);
  const int pos = rowptr[dst] + rank[e];
  emeta[pos] = make_int2(src | (dst << 16), bin << 8);
}

// -------- sorted edge kernel: PD run-boundary prefetch, XCD swizzle --------
__global__ __launch_bounds__(256) void k_edge_sorted(
    const int2* __restrict__ emeta, const unsigned short* __restrict__ LUTh,
    const unsigned short* __restrict__ PDh, const unsigned short* __restrict__ PSh,
    float* __restrict__ agg) {
  const int tid = threadIdx.x;
  const int lane = tid & 63;
  const int w = __builtin_amdgcn_readfirstlane(tid >> 6);
  // bijective XCD swizzle: nwg=3125, q=390, r=5 (m204 formula)
  const int bid = blockIdx.x;
  const int xcd = bid & 7;
  const int idx = bid >> 3;
  const int sb = ((xcd < 5) ? xcd * 391 : 5 * 391 + (xcd - 5) * 390) + idx;
  const int e0 = sb * 128 + w * 32;
  const int u4 = 4 * lane;              // ushort offset: channels 2l, 2l+1
  float m0 = 0.f, m1 = 0.f;
  int cur = -1;
  f32x2 a0 = 0.f, a1 = 0.f;
  uint2 b[4], v[4];
  // PD prefetch: pending row for the next run head
  int pend_dst = (int)((unsigned)emeta[e0].x >> 16);
  uint2 pend = *(const uint2*)&PDh[(pend_dst << 8) + u4];
#pragma unroll
  for (int p = 0; p < 4; ++p) {
    const int2 md = emeta[e0 + p];      // wave-uniform -> s_load_dwordx2
    b[p] = *(const uint2*)&PSh[((md.x & 0xffff) << 8) + u4];
    v[p] = *(const uint2*)&LUTh[md.y + u4];
  }
#pragma unroll
  for (int it = 0; it < 32; ++it) {
    const int sl = it & 3;
    const int dst = (int)((unsigned)emeta[e0 + it].x >> 16);
    if (dst != cur) {                   // uniform: new dst run
      uint2 ad;
      if (dst == pend_dst) ad = pend;   // prefetched at refill time
      else ad = *(const uint2*)&PDh[(dst << 8) + u4];  // fallback
      a0 = bf2_unpack(ad.x);
      a1 = bf2_unpack(ad.y);
      cur = dst;
    }
    const f32x2 bb0 = bf2_unpack(b[sl].x);
    const f32x2 bb1 = bf2_unpack(b[sl].y);
    const f32x2 w0 = bf2_unpack(v[sl].x);
    const f32x2 w1 = bf2_unpack(v[sl].y);
    if (it < 28) {                      // refill slot with edge it+4
      const int2 mn = emeta[e0 + it + 4];
      b[sl] = *(const uint2*)&PSh[((mn.x & 0xffff) << 8) + u4];
      v[sl] = *(const uint2*)&LUTh[mn.y + u4];
      const int d4 = (int)((unsigned)mn.x >> 16);
      const int d3 = (int)((unsigned)emeta[e0 + it + 3].x >> 16);
      if (d4 != d3) {                   // edge it+4 opens a run: prefetch PD
        pend = *(const uint2*)&PDh[(d4 << 8) + u4];
        pend_dst = d4;
      }
    }
    const f32x2 fs0 = (a0 + bb0) + w0;
    const f32x2 fs1 = (a1 + bb1) + w1;
    const float ef0 = __builtin_amdgcn_exp2f(-fs0.x * LOG2E);
    const float ef1 = __builtin_amdgcn_exp2f(-fs1.x * LOG2E);
    const float et0 = __builtin_amdgcn_exp2f(-fabsf(fs0.y) * LOG2E);
    const float et1 = __builtin_amdgcn_exp2f(-fabsf(fs1.y) * LOG2E);
    const float sig0 = __builtin_amdgcn_rcpf(1.f + ef0);
    const float sig1 = __builtin_amdgcn_rcpf(1.f + ef1);
    const float sp0 = fmaxf(fs0.y, 0.f) + LN2 * __builtin_amdgcn_logf(1.f + et0);
    const float sp1 = fmaxf(fs1.y, 0.f) + LN2 * __builtin_amdgcn_logf(1.f + et1);
    m0 = fmaf(sig0, sp0, m0);
    m1 = fmaf(sig1, sp1, m1);
    bool fl = true;
    if (it < 31) fl = ((int)((unsigned)emeta[e0 + it + 1].x >> 16) != dst);
    if (fl) {                           // uniform: end of run -> flush
      atomicAdd(&agg[dst * HH + 2 * lane], m0);
      atomicAdd(&agg[dst * HH + 2 * lane + 1], m1);
      m0 = 0.f;
      m1 = 0.f;
    }
  }
}

// ---------------- per-channel sum / sumsq (float4 rows) ----------------
__global__ __launch_bounds__(256) void k_stats(
    const float* __restrict__ agg, float* __restrict__ stats) {
  const int c4 = (threadIdx.x & 31) * 4;
  const int slice = blockIdx.x * 8 + (threadIdx.x >> 5);
  const int nslices = gridDim.x * 8;
  f32x4 s = (f32x4)0.f, s2 = (f32x4)0.f;
  for (int n = slice; n < NN; n += nslices) {
    const float4 vv = *(const float4*)&agg[n * HH + c4];
    s.x += vv.x; s.y += vv.y; s.z += vv.z; s.w += vv.w;
    s2.x = fmaf(vv.x, vv.x, s2.x);
    s2.y = fmaf(vv.y, vv.y, s2.y);
    s2.z = fmaf(vv.z, vv.z, s2.z);
    s2.w = fmaf(vv.w, vv.w, s2.w);
  }
#pragma unroll
  for (int j = 0; j < 4; ++j) {
    atomicAdd(&stats[c4 + j], s[j]);
    atomicAdd(&stats[HH + c4 + j], s2[j]);
  }
}

// ---------------- batchnorm + residual + relu (layer 1) + zero bufA --------
__global__ __launch_bounds__(256) void k_bn(
    const float* __restrict__ agg, float* __restrict__ hold,
    const float* __restrict__ stats, const float* __restrict__ g,
    const float* __restrict__ b, float* __restrict__ hnew) {
  int t = blockIdx.x * 256 + threadIdx.x;
  if (t >= NH) return;
  const int c = t & 127;
  const float inv_n = 1.f / (float)NN;
  const float mu = stats[c] * inv_n;
  const float var = stats[HH + c] * inv_n - mu * mu;
  const float rs = rsqrtf(var + 1e-5f);
  const float v = (agg[t] - mu) * rs * g[c] + b[c] + hold[t];
  hnew[t] = fmaxf(v, 0.f);
  hold[t] = 0.f;
}

// ---------------- final fc: fused BN2+residual+ReLU then h2 @ fc_w ---------
__global__ __launch_bounds__(256) void k_fc(
    const float* __restrict__ agg, const float* __restrict__ hold,
    const float* __restrict__ stats, const float* __restrict__ g,
    const float* __restrict__ bb, const float* __restrict__ w,
    const float* __restrict__ b, float* __restrict__ out) {
  __shared__ float hs[8][128];
  __shared__ float scale[128], shift[128];
  const int tid = threadIdx.x;
  const int n0 = blockIdx.x * 8;
  if (tid < 128) {
    const float inv_n = 1.f / (float)NN;
    const float mu = stats[tid] * inv_n;
    const float var = stats[128 + tid] * inv_n - mu * mu;
    const float sc = rsqrtf(var + 1e-5f) * g[tid];
    scale[tid] = sc;
    shift[tid] = bb[tid] - mu * sc;
  }
  __syncthreads();
  {
    const int nl = tid >> 5;
    const int k0 = (tid & 31) * 4;
    const int gn = n0 + nl;
    if (gn < NN) {
      const float4 av = *(const float4*)&agg[gn * HH + k0];
      const float4 ov = *(const float4*)&hold[gn * HH + k0];
#pragma unroll
      for (int jj = 0; jj < 4; ++jj) {
        const int k = k0 + jj;
        const float a = (&av.x)[jj], o = (&ov.x)[jj];
        hs[nl][k] = fmaxf(fmaf(a, scale[k], shift[k]) + o, 0.f);
      }
    }
  }
  __syncthreads();
  const int ln = tid >> 5;
  const int m = tid & 31;
  const int n = n0 + ln;
  if (n >= NN || m >= 21) return;
  float acc = b[m];
#pragma unroll 4
  for (int k = 0; k < HH; ++k) acc = fmaf(hs[ln][k], w[k * 21 + m], acc);
  out[n * 21 + m] = acc;
}

extern "C" void kernel_launch(void* const* d_in, const int* in_sizes, int n_in,
                              void* d_out, int out_size, void* d_ws, size_t ws_size,
                              hipStream_t stream) {
  const float* x      = (const float*)d_in[0];
  const float* eattr  = (const float*)d_in[1];
  const float* node_w = (const float*)d_in[2];
  const float* node_b = (const float*)d_in[3];
  const float* f1w    = (const float*)d_in[4];
  const float* f1b    = (const float*)d_in[5];
  const float* s1w    = (const float*)d_in[6];
  const float* s1b    = (const float*)d_in[7];
  const float* bn1g   = (const float*)d_in[8];
  const float* bn1b   = (const float*)d_in[9];
  const float* f2w    = (const float*)d_in[10];
  const float* f2b    = (const float*)d_in[11];
  const float* s2w    = (const float*)d_in[12];
  const float* s2b    = (const float*)d_in[13];
  const float* bn2g   = (const float*)d_in[14];
  const float* bn2b   = (const float*)d_in[15];
  const float* fcw    = (const float*)d_in[16];
  const float* fcb    = (const float*)d_in[17];
  const int*   ei     = (const int*)d_in[18];
  float* out = (float*)d_out;

  float* ws   = (float*)d_ws;
  float* bufA = ws;                          // h0, later agg2
  float* bufB = ws + NH;                     // agg1 -> h1
  unsigned short* PDh = (unsigned short*)(ws + 2 * (size_t)NH);  // [NN][256] bf16
  unsigned short* PSh = (unsigned short*)(ws + 3 * (size_t)NH);  // [NN][256] bf16
  float* stats1 = ws + 4 * (size_t)NH;       // 256
  float* stats2 = stats1 + 256;              // 256
  int*   deg    = (int*)(stats2 + 256);      // NN
  int*   rowptr = deg + NN;                  // NN
  int*   rank   = rowptr + NN;               // NE
  int2*  emeta  = (int2*)(rank + NE);        // NE int2
  unsigned short* Wf1 = (unsigned short*)(emeta + NE);   // 65536 bf16
  float* bv1    = (float*)(Wf1 + 65536);     // 512
  unsigned short* Wf2 = (unsigned short*)(bv1 + 512);    // 65536 bf16
  float* bv2    = (float*)(Wf2 + 65536);     // 512
  unsigned short* lut1 = (unsigned short*)(bv2 + 512);   // (NBINS+1)*256 bf16
  unsigned short* lut2 = lut1 + (size_t)(NBINS + 1) * 256;

  const int g_edge  = NE / 128;   // 3125
  const int g_bn    = (NH + 255) / 256;
  const int g_e256  = (NE + 255) / 256;     // 1563
  const dim3 g_gemm((NN + 127) / 128, 4);
  const dim3 g_prep(1563, 3);               // planes 0/1: prep; 2: hist

  // ---- deg zeroing must precede hist's atomics (separate dispatch) ----
  hipMemsetAsync(deg, 0, NN * 4, stream);

  // ---- fused prep + hist ----
  k_prep<<<g_prep, 256, 0, stream>>>(f1w, s1w, f1b, s1b, f2w, s2w, f2b, s2b,
                                     Wf1, bv1, lut1, Wf2, bv2, lut2,
                                     stats1, deg, ei, rank);

  // ---- scan + atomic-free scatter ----
  k_scan<<<1, 1024, 0, stream>>>(deg, rowptr);
  k_scatter<<<g_e256, 256, 0, stream>>>(ei, eattr, rowptr, rank, emeta);

  // ---- layer 1 (node-embed fused; y==1 blocks zero bufB) ----
  k_gemm1<<<g_gemm, 256, 0, stream>>>(x, node_w, node_b, Wf1, bv1, bufA,
                                      PDh, PSh, bufB);
  k_edge_sorted<<<g_edge, 256, 0, stream>>>(emeta, lut1, PDh, PSh, bufB);
  k_stats<<<128, 256, 0, stream>>>(bufB, stats1);
  k_bn<<<g_bn, 256, 0, stream>>>(bufB, bufA, stats1, bn1g, bn1b, bufB);

  // ---- layer 2 ----
  k_gemm_mfma<<<g_gemm, 256, 0, stream>>>(bufB, Wf2, bv2, PDh, PSh);
  k_edge_sorted<<<g_edge, 256, 0, stream>>>(emeta, lut2, PDh, PSh, bufA);
  k_stats<<<128, 256, 0, stream>>>(bufA, stats2);

  // ---- final fc (BN2+residual+ReLU fused) ----
  k_fc<<<(NN + 7) / 8, 256, 0, stream>>>(bufA, bufB, stats2, bn2g, bn2b,
                                         fcw, fcb, out);
}

// Round 20
// 282.248 us; speedup vs baseline: 1.6665x; 1.6665x over previous
//
#include <hip/hip_runtime.h>
#include <hip/hip_bf16.h>
#include <math.h>

#define NN 25000
#define NE 400000
#define HH 128
#define NH (NN*HH)
#define NBINS 2048

#define GS_STEP  (8.0f/15.0f)
#define GS_COEFF (-1.7578125f)
#define LOG2E    1.442695041f
#define LN2      0.6931471806f
#define BINSC    ((float)NBINS / 8.0f)

typedef float f32x2 __attribute__((ext_vector_type(2)));
typedef float f32x4 __attribute__((ext_vector_type(4)));
typedef short bf16x8 __attribute__((ext_vector_type(8)));

__device__ __forceinline__ f32x2 bf2_unpack(unsigned int u) {
  union { unsigned int i; float f; } lo, hi;
  lo.i = u << 16;
  hi.i = u & 0xffff0000u;
  f32x2 r; r.x = lo.f; r.y = hi.f;
  return r;
}

__device__ __forceinline__ unsigned short bf16_of(float f) {
  return __hip_bfloat16_raw(__float2bfloat16(f)).x;
}

// --- fused prep: weight pack + bf16 LUT + (plane y==2) hist ---
__global__ __launch_bounds__(256) void k_prep(
    const float* __restrict__ f1w, const float* __restrict__ s1w,
    const float* __restrict__ f1b, const float* __restrict__ s1b,
    const float* __restrict__ f2w, const float* __restrict__ s2w,
    const float* __restrict__ f2b, const float* __restrict__ s2b,
    unsigned short* __restrict__ Wf1, float* __restrict__ bv1,
    unsigned short* __restrict__ L1,
    unsigned short* __restrict__ Wf2, float* __restrict__ bv2,
    unsigned short* __restrict__ L2,
    int* __restrict__ deg, const int* __restrict__ ei,
    int* __restrict__ rank) {
  const int bx = blockIdx.x;
  const int tid = threadIdx.x;
  if (blockIdx.y == 2) {   // hist plane: count degrees + record ranks
    int e = bx * 256 + tid;
    if (e < NE) rank[e] = atomicAdd(&deg[ei[NE + e]], 1);
    return;
  }
  if (bx >= 1281) return;  // prep planes use x < 1281 only
  const int layer = blockIdx.y;
  const float* fw = layer ? f2w : f1w;
  const float* sw = layer ? s2w : s1w;
  const float* fb = layer ? f2b : f1b;
  const float* sb = layer ? s2b : s1b;
  unsigned short* Wf = layer ? Wf2 : Wf1;
  float* biasv = layer ? bv2 : bv1;
  unsigned short* LUT = layer ? L2 : L1;
  if (bx < 256) {
    const int t = bx * 256 + tid;
    if (t < 512) biasv[t] = (t < 256) ? ((t & 1) ? sb[t >> 1] : fb[t >> 1]) : 0.f;
    const int j = t & 7;
    const int lane = (t >> 3) & 63;
    const int kt = (t >> 9) & 3;
    const int nt = t >> 11;
    const int k = 32 * kt + 8 * (lane >> 4) + j;
    const int c = 16 * nt + (lane & 15);
    const int cc = c & 255;
    const int row = ((c >= 256) ? 128 : 0) + k;
    const float* m = (cc & 1) ? sw : fw;
    Wf[t] = bf16_of(m[row * HH + (cc >> 1)]);
  } else {
    const int bin = (bx - 256) * 2 + (tid >> 7);
    if (bin > NBINS) return;
    const int j = tid & 127;
    const float* fw3 = fw + 256 * HH;
    const float* sw3 = sw + 256 * HH;
    const float d = (float)bin * (8.0f / (float)NBINS);
    f32x2 acc = 0.f;
#pragma unroll
    for (int k = 0; k < 16; ++k) {
      float tt = d - (float)k * GS_STEP;
      float ee = __expf(GS_COEFF * tt * tt);
      f32x2 w;
      w.x = fw3[k * HH + j];
      w.y = sw3[k * HH + j];
      acc = __builtin_elementwise_fma((f32x2)(ee), w, acc);
    }
    *(unsigned int*)&LUT[bin * 256 + 2 * j] =
        (unsigned int)bf16_of(acc.x) | ((unsigned int)bf16_of(acc.y) << 16);
  }
}

// ============ shared MFMA core: 128x128 tile, 4 waves; bf16 PD+PS ==========
__device__ __forceinline__ void gemm_core(
    const unsigned short* As, const unsigned short* __restrict__ Wfrag,
    const float* __restrict__ biasv, int n0, int bn0,
    unsigned short* __restrict__ PDh, unsigned short* __restrict__ PSh,
    int tid) {
  const int w = tid >> 6;
  const int lane = tid & 63;
  const int mt0 = 2 * w;
  f32x4 acc[2][8];
#pragma unroll
  for (int mi = 0; mi < 2; ++mi)
#pragma unroll
    for (int nt = 0; nt < 8; ++nt) acc[mi][nt] = (f32x4)0.f;
  const int ntg0 = bn0 >> 4;
#pragma unroll
  for (int kt = 0; kt < 4; ++kt) {
    const bf16x8 a0 = *(const bf16x8*)&As[((mt0 * 4 + kt) * 64 + lane) * 8];
    const bf16x8 a1 = *(const bf16x8*)&As[(((mt0 + 1) * 4 + kt) * 64 + lane) * 8];
#pragma unroll
    for (int nt = 0; nt < 8; ++nt) {
      const bf16x8 b =
          *(const bf16x8*)&Wfrag[(((ntg0 + nt) * 4 + kt) * 64 + lane) * 8];
      acc[0][nt] = __builtin_amdgcn_mfma_f32_16x16x32_bf16(a0, b, acc[0][nt], 0, 0, 0);
      acc[1][nt] = __builtin_amdgcn_mfma_f32_16x16x32_bf16(a1, b, acc[1][nt], 0, 0, 0);
    }
  }
  const int colloc = lane & 15;
  const int rbase = (lane >> 4) * 4;
  const bool isPD = (bn0 < 256);
#pragma unroll
  for (int mi = 0; mi < 2; ++mi) {
#pragma unroll
    for (int nt = 0; nt < 8; ++nt) {
      const int c = bn0 + nt * 16 + colloc;
      const float bias = biasv[c];
#pragma unroll
      for (int r = 0; r < 4; ++r) {
        const int n = n0 + (mt0 + mi) * 16 + rbase + r;
        if (n < NN) {
          const float vv = acc[mi][nt][r] + bias;
          if (isPD) PDh[n * 256 + c] = bf16_of(vv);
          else PSh[n * 256 + (c - 256)] = bf16_of(vv);
        }
      }
    }
  }
}

// ---------------- layer-1 GEMM: fused node-embed staging + bufB zeroing ----
__global__ __launch_bounds__(256) void k_gemm1(
    const float* __restrict__ x, const float* __restrict__ nw,
    const float* __restrict__ nb, const unsigned short* __restrict__ Wfrag,
    const float* __restrict__ biasv, float* __restrict__ h0,
    unsigned short* __restrict__ PDh, unsigned short* __restrict__ PSh,
    float* __restrict__ zb) {
  __shared__ unsigned short As[128 * 128];
  __shared__ float wn[6 * 128 + 128];
  const int tid = threadIdx.x;
  const int n0 = blockIdx.x * 128;
  const int bn0 = blockIdx.y * 128;
  const bool wr_h0 = (blockIdx.y == 0);
  for (int i = tid; i < 6 * 128 + 128; i += 256)
    wn[i] = (i < 6 * 128) ? nw[i] : nb[i - 6 * 128];
  if (blockIdx.y == 1) {
    const float4 z = {0.f, 0.f, 0.f, 0.f};
    for (int i = tid; i < 128 * 32; i += 256) {
      const int n = n0 + (i >> 5);
      if (n < NN) *(float4*)&zb[n * HH + (i & 31) * 4] = z;
    }
  }
  __syncthreads();
  {
    const int tn = tid >> 2;
    const int cj = tid & 3;
#pragma unroll
    for (int ii = 0; ii < 2; ++ii) {
      const int n = tn + 64 * ii;
      const int gn = n0 + n;
      float xr[6];
      if (gn < NN) {
#pragma unroll
        for (int q = 0; q < 6; ++q) xr[q] = x[gn * 6 + q];
      }
#pragma unroll
      for (int i = 0; i < 4; ++i) {
        const int c = cj + 4 * i;
        bf16x8 bv = (bf16x8)0;
        if (gn < NN) {
          float4 r0, r1;
#pragma unroll
          for (int j = 0; j < 8; ++j) {
            const int k = c * 8 + j;
            float acc = wn[6 * 128 + k];
#pragma unroll
            for (int q = 0; q < 6; ++q) acc = fmaf(xr[q], wn[q * 128 + k], acc);
            if (j < 4) (&r0.x)[j] = acc; else (&r1.x)[j - 4] = acc;
            bv[j] = (short)bf16_of(acc);
          }
          if (wr_h0) {
            *(float4*)&h0[gn * HH + c * 8] = r0;
            *(float4*)&h0[gn * HH + c * 8 + 4] = r1;
          }
        }
        const int slot = ((n >> 4) * 4 + (c >> 2)) * 64 + (n & 15) + 16 * (c & 3);
        *(bf16x8*)&As[slot * 8] = bv;
      }
    }
  }
  __syncthreads();
  gemm_core(As, Wfrag, biasv, n0, bn0, PDh, PSh, tid);
}

// ---------------- layer-2 GEMM: plain h input ------------------------------
__global__ __launch_bounds__(256) void k_gemm_mfma(
    const float* __restrict__ h, const unsigned short* __restrict__ Wfrag,
    const float* __restrict__ biasv,
    unsigned short* __restrict__ PDh, unsigned short* __restrict__ PSh) {
  __shared__ unsigned short As[128 * 128];
  const int tid = threadIdx.x;
  const int n0 = blockIdx.x * 128;
  const int bn0 = blockIdx.y * 128;
  {
    const int tn = tid >> 2;
    const int cj = tid & 3;
#pragma unroll
    for (int ii = 0; ii < 2; ++ii) {
      const int n = tn + 64 * ii;
      const int gn = n0 + n;
#pragma unroll
      for (int i = 0; i < 4; ++i) {
        const int c = cj + 4 * i;
        bf16x8 bv;
        if (gn < NN) {
          const float4 p0 = *(const float4*)&h[gn * HH + c * 8];
          const float4 p1 = *(const float4*)&h[gn * HH + c * 8 + 4];
          bv[0] = (short)bf16_of(p0.x); bv[1] = (short)bf16_of(p0.y);
          bv[2] = (short)bf16_of(p0.z); bv[3] = (short)bf16_of(p0.w);
          bv[4] = (short)bf16_of(p1.x); bv[5] = (short)bf16_of(p1.y);
          bv[6] = (short)bf16_of(p1.z); bv[7] = (short)bf16_of(p1.w);
        } else {
          bv = (bf16x8)0;
        }
        const int slot = ((n >> 4) * 4 + (c >> 2)) * 64 + (n & 15) + 16 * (c & 3);
        *(bf16x8*)&As[slot * 8] = bv;
      }
    }
  }
  __syncthreads();
  gemm_core(As, Wfrag, biasv, n0, bn0, PDh, PSh, tid);
}

__global__ __launch_bounds__(1024) void k_scan(
    const int* __restrict__ deg, int* __restrict__ rowptr) {
  __shared__ int part[1024];
  const int tid = threadIdx.x;
  const int CH = (NN + 1023) / 1024;
  const int base = tid * CH;
  int s = 0;
  for (int i = 0; i < CH; ++i) {
    int n = base + i;
    if (n < NN) s += deg[n];
  }
  part[tid] = s;
  __syncthreads();
  for (int off = 1; off < 1024; off <<= 1) {
    int t = (tid >= off) ? part[tid - off] : 0;
    __syncthreads();
    part[tid] += t;
    __syncthreads();
  }
  int run = part[tid] - s;
  for (int i = 0; i < CH; ++i) {
    int n = base + i;
    if (n < NN) {
      rowptr[n] = run;
      run += deg[n];
    }
  }
}

// scatter: atomic-free; pos = rowptr[dst] + rank[e]; 8B packed metadata
__global__ __launch_bounds__(256) void k_scatter(
    const int* __restrict__ ei, const float* __restrict__ eattr,
    const int* __restrict__ rowptr, const int* __restrict__ rank,
    int2* __restrict__ emeta) {
  int e = blockIdx.x * 256 + threadIdx.x;
  if (e >= NE) return;
  const int dst = ei[NE + e];
  const int src = ei[e];
  const int bin = (int)(eattr[e] * BINSC + 0.5f);
  const int pos = rowptr[dst] + rank[e];
  emeta[pos] = make_int2(src | (dst << 16), bin << 8);
}

// -------- sorted edge kernel: PD run-boundary prefetch, XCD swizzle --------
__global__ __launch_bounds__(256) void k_edge_sorted(
    const int2* __restrict__ emeta, const unsigned short* __restrict__ LUTh,
    const unsigned short* __restrict__ PDh, const unsigned short* __restrict__ PSh,
    float* __restrict__ agg) {
  const int tid = threadIdx.x;
  const int lane = tid & 63;
  const int w = __builtin_amdgcn_readfirstlane(tid >> 6);
  const int bid = blockIdx.x;
  const int xcd = bid & 7;
  const int idx = bid >> 3;
  const int sb = ((xcd < 5) ? xcd * 391 : 5 * 391 + (xcd - 5) * 390) + idx;
  const int e0 = sb * 128 + w * 32;
  const int u4 = 4 * lane;
  float m0 = 0.f, m1 = 0.f;
  int cur = -1;
  f32x2 a0 = 0.f, a1 = 0.f;
  uint2 b[4], v[4];
  int pend_dst = (int)((unsigned)emeta[e0].x >> 16);
  uint2 pend = *(const uint2*)&PDh[(pend_dst << 8) + u4];
#pragma unroll
  for (int p = 0; p < 4; ++p) {
    const int2 md = emeta[e0 + p];
    b[p] = *(const uint2*)&PSh[((md.x & 0xffff) << 8) + u4];
    v[p] = *(const uint2*)&LUTh[md.y + u4];
  }
#pragma unroll
  for (int it = 0; it < 32; ++it) {
    const int sl = it & 3;
    const int dst = (int)((unsigned)emeta[e0 + it].x >> 16);
    if (dst != cur) {
      uint2 ad;
      if (dst == pend_dst) ad = pend;
      else ad = *(const uint2*)&PDh[(dst << 8) + u4];
      a0 = bf2_unpack(ad.x);
      a1 = bf2_unpack(ad.y);
      cur = dst;
    }
    const f32x2 bb0 = bf2_unpack(b[sl].x);
    const f32x2 bb1 = bf2_unpack(b[sl].y);
    const f32x2 w0 = bf2_unpack(v[sl].x);
    const f32x2 w1 = bf2_unpack(v[sl].y);
    if (it < 28) {
      const int2 mn = emeta[e0 + it + 4];
      b[sl] = *(const uint2*)&PSh[((mn.x & 0xffff) << 8) + u4];
      v[sl] = *(const uint2*)&LUTh[mn.y + u4];
      const int d4 = (int)((unsigned)mn.x >> 16);
      const int d3 = (int)((unsigned)emeta[e0 + it + 3].x >> 16);
      if (d4 != d3) {
        pend = *(const uint2*)&PDh[(d4 << 8) + u4];
        pend_dst = d4;
      }
    }
    const f32x2 fs0 = (a0 + bb0) + w0;
    const f32x2 fs1 = (a1 + bb1) + w1;
    const float ef0 = __builtin_amdgcn_exp2f(-fs0.x * LOG2E);
    const float ef1 = __builtin_amdgcn_exp2f(-fs1.x * LOG2E);
    const float et0 = __builtin_amdgcn_exp2f(-fabsf(fs0.y) * LOG2E);
    const float et1 = __builtin_amdgcn_exp2f(-fabsf(fs1.y) * LOG2E);
    const float sig0 = __builtin_amdgcn_rcpf(1.f + ef0);
    const float sig1 = __builtin_amdgcn_rcpf(1.f + ef1);
    const float sp0 = fmaxf(fs0.y, 0.f) + LN2 * __builtin_amdgcn_logf(1.f + et0);
    const float sp1 = fmaxf(fs1.y, 0.f) + LN2 * __builtin_amdgcn_logf(1.f + et1);
    m0 = fmaf(sig0, sp0, m0);
    m1 = fmaf(sig1, sp1, m1);
    bool fl = true;
    if (it < 31) fl = ((int)((unsigned)emeta[e0 + it + 1].x >> 16) != dst);
    if (fl) {
      atomicAdd(&agg[dst * HH + 2 * lane], m0);
      atomicAdd(&agg[dst * HH + 2 * lane + 1], m1);
      m0 = 0.f;
      m1 = 0.f;
    }
  }
}

// ------- stats stage 1: block-local reduce -> partials (NO atomics) -------
__global__ __launch_bounds__(256) void k_stats1(
    const float* __restrict__ agg, float* __restrict__ partials) {
  __shared__ float ls[8][128], ls2[8][128];
  const int tid = threadIdx.x;
  const int sub = tid >> 5;             // 0..7
  const int c4 = (tid & 31) * 4;
  f32x4 s = (f32x4)0.f, s2 = (f32x4)0.f;
  for (int n = blockIdx.x * 8 + sub; n < NN; n += 2048) {
    const float4 vv = *(const float4*)&agg[n * HH + c4];
    s.x += vv.x; s.y += vv.y; s.z += vv.z; s.w += vv.w;
    s2.x = fmaf(vv.x, vv.x, s2.x);
    s2.y = fmaf(vv.y, vv.y, s2.y);
    s2.z = fmaf(vv.z, vv.z, s2.z);
    s2.w = fmaf(vv.w, vv.w, s2.w);
  }
#pragma unroll
  for (int j = 0; j < 4; ++j) {
    ls[sub][c4 + j] = s[j];
    ls2[sub][c4 + j] = s2[j];
  }
  __syncthreads();
  if (tid < 128) {
    float t = 0.f, t2 = 0.f;
#pragma unroll
    for (int r = 0; r < 8; ++r) {
      t += ls[r][tid];
      t2 += ls2[r][tid];
    }
    partials[blockIdx.x * 256 + tid] = t;
    partials[blockIdx.x * 256 + 128 + tid] = t2;
  }
}

// ------- stats stage 2: reduce 256 partial blocks -> stats (plain store) ---
__global__ __launch_bounds__(256) void k_stats2(
    const float* __restrict__ partials, float* __restrict__ stats) {
  const int tid = threadIdx.x;
  float t = 0.f;
  for (int b = 0; b < 256; ++b) t += partials[b * 256 + tid];
  stats[tid] = t;
}

// ---------------- batchnorm + residual + relu (layer 1) + zero bufA --------
__global__ __launch_bounds__(256) void k_bn(
    const float* __restrict__ agg, float* __restrict__ hold,
    const float* __restrict__ stats, const float* __restrict__ g,
    const float* __restrict__ b, float* __restrict__ hnew) {
  int t = blockIdx.x * 256 + threadIdx.x;
  if (t >= NH) return;
  const int c = t & 127;
  const float inv_n = 1.f / (float)NN;
  const float mu = stats[c] * inv_n;
  const float var = stats[HH + c] * inv_n - mu * mu;
  const float rs = rsqrtf(var + 1e-5f);
  const float v = (agg[t] - mu) * rs * g[c] + b[c] + hold[t];
  hnew[t] = fmaxf(v, 0.f);
  hold[t] = 0.f;
}

// ---------------- final fc: fused BN2+residual+ReLU then h2 @ fc_w ---------
__global__ __launch_bounds__(256) void k_fc(
    const float* __restrict__ agg, const float* __restrict__ hold,
    const float* __restrict__ stats, const float* __restrict__ g,
    const float* __restrict__ bb, const float* __restrict__ w,
    const float* __restrict__ b, float* __restrict__ out) {
  __shared__ float hs[8][128];
  __shared__ float scale[128], shift[128];
  const int tid = threadIdx.x;
  const int n0 = blockIdx.x * 8;
  if (tid < 128) {
    const float inv_n = 1.f / (float)NN;
    const float mu = stats[tid] * inv_n;
    const float var = stats[128 + tid] * inv_n - mu * mu;
    const float sc = rsqrtf(var + 1e-5f) * g[tid];
    scale[tid] = sc;
    shift[tid] = bb[tid] - mu * sc;
  }
  __syncthreads();
  {
    const int nl = tid >> 5;
    const int k0 = (tid & 31) * 4;
    const int gn = n0 + nl;
    if (gn < NN) {
      const float4 av = *(const float4*)&agg[gn * HH + k0];
      const float4 ov = *(const float4*)&hold[gn * HH + k0];
#pragma unroll
      for (int jj = 0; jj < 4; ++jj) {
        const int k = k0 + jj;
        const float a = (&av.x)[jj], o = (&ov.x)[jj];
        hs[nl][k] = fmaxf(fmaf(a, scale[k], shift[k]) + o, 0.f);
      }
    }
  }
  __syncthreads();
  const int ln = tid >> 5;
  const int m = tid & 31;
  const int n = n0 + ln;
  if (n >= NN || m >= 21) return;
  float acc = b[m];
#pragma unroll 4
  for (int k = 0; k < HH; ++k) acc = fmaf(hs[ln][k], w[k * 21 + m], acc);
  out[n * 21 + m] = acc;
}

extern "C" void kernel_launch(void* const* d_in, const int* in_sizes, int n_in,
                              void* d_out, int out_size, void* d_ws, size_t ws_size,
                              hipStream_t stream) {
  const float* x      = (const float*)d_in[0];
  const float* eattr  = (const float*)d_in[1];
  const float* node_w = (const float*)d_in[2];
  const float* node_b = (const float*)d_in[3];
  const float* f1w    = (const float*)d_in[4];
  const float* f1b    = (const float*)d_in[5];
  const float* s1w    = (const float*)d_in[6];
  const float* s1b    = (const float*)d_in[7];
  const float* bn1g   = (const float*)d_in[8];
  const float* bn1b   = (const float*)d_in[9];
  const float* f2w    = (const float*)d_in[10];
  const float* f2b    = (const float*)d_in[11];
  const float* s2w    = (const float*)d_in[12];
  const float* s2b    = (const float*)d_in[13];
  const float* bn2g   = (const float*)d_in[14];
  const float* bn2b   = (const float*)d_in[15];
  const float* fcw    = (const float*)d_in[16];
  const float* fcb    = (const float*)d_in[17];
  const int*   ei     = (const int*)d_in[18];
  float* out = (float*)d_out;

  float* ws   = (float*)d_ws;
  float* bufA = ws;                          // h0, later agg2
  float* bufB = ws + NH;                     // agg1 -> h1
  unsigned short* PDh = (unsigned short*)(ws + 2 * (size_t)NH);  // [NN][256] bf16
  unsigned short* PSh = (unsigned short*)(ws + 3 * (size_t)NH);  // [NN][256] bf16
  float* stats1 = ws + 4 * (size_t)NH;       // 256
  float* stats2 = stats1 + 256;              // 256
  float* partials = stats2 + 256;            // 256*256
  int*   deg    = (int*)(partials + 256 * 256);  // NN
  int*   rowptr = deg + NN;                  // NN
  int*   rank   = rowptr + NN;               // NE
  int2*  emeta  = (int2*)(rank + NE);        // NE int2
  unsigned short* Wf1 = (unsigned short*)(emeta + NE);   // 65536 bf16
  float* bv1    = (float*)(Wf1 + 65536);     // 512
  unsigned short* Wf2 = (unsigned short*)(bv1 + 512);    // 65536 bf16
  float* bv2    = (float*)(Wf2 + 65536);     // 512
  unsigned short* lut1 = (unsigned short*)(bv2 + 512);   // (NBINS+1)*256 bf16
  unsigned short* lut2 = lut1 + (size_t)(NBINS + 1) * 256;

  const int g_edge  = NE / 128;   // 3125
  const int g_bn    = (NH + 255) / 256;
  const int g_e256  = (NE + 255) / 256;     // 1563
  const dim3 g_gemm((NN + 127) / 128, 4);
  const dim3 g_prep(1563, 3);               // planes 0/1: prep; 2: hist

  // ---- deg zeroing must precede hist's atomics ----
  hipMemsetAsync(deg, 0, NN * 4, stream);

  // ---- fused prep + hist ----
  k_prep<<<g_prep, 256, 0, stream>>>(f1w, s1w, f1b, s1b, f2w, s2w, f2b, s2b,
                                     Wf1, bv1, lut1, Wf2, bv2, lut2,
                                     deg, ei, rank);

  // ---- scan + atomic-free scatter ----
  k_scan<<<1, 1024, 0, stream>>>(deg, rowptr);
  k_scatter<<<g_e256, 256, 0, stream>>>(ei, eattr, rowptr, rank, emeta);

  // ---- layer 1 (node-embed fused; y==1 blocks zero bufB) ----
  k_gemm1<<<g_gemm, 256, 0, stream>>>(x, node_w, node_b, Wf1, bv1, bufA,
                                      PDh, PSh, bufB);
  k_edge_sorted<<<g_edge, 256, 0, stream>>>(emeta, lut1, PDh, PSh, bufB);
  k_stats1<<<256, 256, 0, stream>>>(bufB, partials);
  k_stats2<<<1, 256, 0, stream>>>(partials, stats1);
  k_bn<<<g_bn, 256, 0, stream>>>(bufB, bufA, stats1, bn1g, bn1b, bufB);

  // ---- layer 2 ----
  k_gemm_mfma<<<g_gemm, 256, 0, stream>>>(bufB, Wf2, bv2, PDh, PSh);
  k_edge_sorted<<<g_edge, 256, 0, stream>>>(emeta, lut2, PDh, PSh, bufA);
  k_stats1<<<256, 256, 0, stream>>>(bufA, partials);
  k_stats2<<<1, 256, 0, stream>>>(partials, stats2);
  k_fc<<<(NN + 7) / 8, 256, 0, stream>>>(bufA, bufB, stats2, bn2g, bn2b,
                                         fcw, fcb, out);
}

// Round 21
// 267.160 us; speedup vs baseline: 1.7606x; 1.0565x over previous
//
#include <hip/hip_runtime.h>
#include <hip/hip_bf16.h>
#include <math.h>

#define NN 25000
#define NE 400000
#define HH 128
#define NH (NN*HH)
#define NBINS 2048

#define GS_STEP  (8.0f/15.0f)
#define GS_COEFF (-1.7578125f)
#define LOG2E    1.442695041f
#define LN2      0.6931471806f
#define BINSC    ((float)NBINS / 8.0f)

typedef float f32x2 __attribute__((ext_vector_type(2)));
typedef float f32x4 __attribute__((ext_vector_type(4)));
typedef short bf16x8 __attribute__((ext_vector_type(8)));

__device__ __forceinline__ f32x2 bf2_unpack(unsigned int u) {
  union { unsigned int i; float f; } lo, hi;
  lo.i = u << 16;
  hi.i = u & 0xffff0000u;
  f32x2 r; r.x = lo.f; r.y = hi.f;
  return r;
}

__device__ __forceinline__ unsigned short bf16_of(float f) {
  return __hip_bfloat16_raw(__float2bfloat16(f)).x;
}

// --------- prep: weight pack + bf16 LUT + deg zeroing (no hist) -----------
__global__ __launch_bounds__(256) void k_prep(
    const float* __restrict__ f1w, const float* __restrict__ s1w,
    const float* __restrict__ f1b, const float* __restrict__ s1b,
    const float* __restrict__ f2w, const float* __restrict__ s2w,
    const float* __restrict__ f2b, const float* __restrict__ s2b,
    unsigned short* __restrict__ Wf1, float* __restrict__ bv1,
    unsigned short* __restrict__ L1,
    unsigned short* __restrict__ Wf2, float* __restrict__ bv2,
    unsigned short* __restrict__ L2, int* __restrict__ deg) {
  const int bx = blockIdx.x;
  const int tid = threadIdx.x;
  const int layer = blockIdx.y;
  const float* fw = layer ? f2w : f1w;
  const float* sw = layer ? s2w : s1w;
  const float* fb = layer ? f2b : f1b;
  const float* sb = layer ? s2b : s1b;
  unsigned short* Wf = layer ? Wf2 : Wf1;
  float* biasv = layer ? bv2 : bv1;
  unsigned short* LUT = layer ? L2 : L1;
  if (bx < 256) {
    if (layer == 0 && bx < 98) {   // zero deg[25000]
      const int i = bx * 256 + tid;
      if (i < NN) deg[i] = 0;
    }
    const int t = bx * 256 + tid;
    if (t < 512) biasv[t] = (t < 256) ? ((t & 1) ? sb[t >> 1] : fb[t >> 1]) : 0.f;
    const int j = t & 7;
    const int lane = (t >> 3) & 63;
    const int kt = (t >> 9) & 3;
    const int nt = t >> 11;
    const int k = 32 * kt + 8 * (lane >> 4) + j;
    const int c = 16 * nt + (lane & 15);
    const int cc = c & 255;
    const int row = ((c >= 256) ? 128 : 0) + k;
    const float* m = (cc & 1) ? sw : fw;
    Wf[t] = bf16_of(m[row * HH + (cc >> 1)]);
  } else {
    const int bin = (bx - 256) * 2 + (tid >> 7);
    if (bin > NBINS) return;
    const int j = tid & 127;
    const float* fw3 = fw + 256 * HH;
    const float* sw3 = sw + 256 * HH;
    const float d = (float)bin * (8.0f / (float)NBINS);
    f32x2 acc = 0.f;
#pragma unroll
    for (int k = 0; k < 16; ++k) {
      float tt = d - (float)k * GS_STEP;
      float ee = __expf(GS_COEFF * tt * tt);
      f32x2 w;
      w.x = fw3[k * HH + j];
      w.y = sw3[k * HH + j];
      acc = __builtin_elementwise_fma((f32x2)(ee), w, acc);
    }
    *(unsigned int*)&LUT[bin * 256 + 2 * j] =
        (unsigned int)bf16_of(acc.x) | ((unsigned int)bf16_of(acc.y) << 16);
  }
}

// ============ shared MFMA core: 128x128 tile, 4 waves; bf16 PD+PS ==========
__device__ __forceinline__ void gemm_core(
    const unsigned short* As, const unsigned short* __restrict__ Wfrag,
    const float* __restrict__ biasv, int n0, int bn0,
    unsigned short* __restrict__ PDh, unsigned short* __restrict__ PSh,
    int tid) {
  const int w = tid >> 6;
  const int lane = tid & 63;
  const int mt0 = 2 * w;
  f32x4 acc[2][8];
#pragma unroll
  for (int mi = 0; mi < 2; ++mi)
#pragma unroll
    for (int nt = 0; nt < 8; ++nt) acc[mi][nt] = (f32x4)0.f;
  const int ntg0 = bn0 >> 4;
#pragma unroll
  for (int kt = 0; kt < 4; ++kt) {
    const bf16x8 a0 = *(const bf16x8*)&As[((mt0 * 4 + kt) * 64 + lane) * 8];
    const bf16x8 a1 = *(const bf16x8*)&As[(((mt0 + 1) * 4 + kt) * 64 + lane) * 8];
#pragma unroll
    for (int nt = 0; nt < 8; ++nt) {
      const bf16x8 b =
          *(const bf16x8*)&Wfrag[(((ntg0 + nt) * 4 + kt) * 64 + lane) * 8];
      acc[0][nt] = __builtin_amdgcn_mfma_f32_16x16x32_bf16(a0, b, acc[0][nt], 0, 0, 0);
      acc[1][nt] = __builtin_amdgcn_mfma_f32_16x16x32_bf16(a1, b, acc[1][nt], 0, 0, 0);
    }
  }
  const int colloc = lane & 15;
  const int rbase = (lane >> 4) * 4;
  const bool isPD = (bn0 < 256);
#pragma unroll
  for (int mi = 0; mi < 2; ++mi) {
#pragma unroll
    for (int nt = 0; nt < 8; ++nt) {
      const int c = bn0 + nt * 16 + colloc;
      const float bias = biasv[c];
#pragma unroll
      for (int r = 0; r < 4; ++r) {
        const int n = n0 + (mt0 + mi) * 16 + rbase + r;
        if (n < NN) {
          const float vv = acc[mi][nt][r] + bias;
          if (isPD) PDh[n * 256 + c] = bf16_of(vv);
          else PSh[n * 256 + (c - 256)] = bf16_of(vv);
        }
      }
    }
  }
}

// --- layer-1 GEMM + (plane y==4) hist: overlap latency-bound atomics -------
__global__ __launch_bounds__(256) void k_gemm1(
    const float* __restrict__ x, const float* __restrict__ nw,
    const float* __restrict__ nb, const unsigned short* __restrict__ Wfrag,
    const float* __restrict__ biasv, float* __restrict__ h0,
    unsigned short* __restrict__ PDh, unsigned short* __restrict__ PSh,
    float* __restrict__ zb, const int* __restrict__ ei,
    int* __restrict__ deg, int* __restrict__ rank) {
  if (blockIdx.y == 4) {   // hist plane: count degrees + record ranks
    int e = blockIdx.x * 256 + threadIdx.x;
    if (e < NE) rank[e] = atomicAdd(&deg[ei[NE + e]], 1);
    return;
  }
  if (blockIdx.x >= 196) return;   // gemm planes use x < 196 only
  __shared__ unsigned short As[128 * 128];
  __shared__ float wn[6 * 128 + 128];
  const int tid = threadIdx.x;
  const int n0 = blockIdx.x * 128;
  const int bn0 = blockIdx.y * 128;
  const bool wr_h0 = (blockIdx.y == 0);
  for (int i = tid; i < 6 * 128 + 128; i += 256)
    wn[i] = (i < 6 * 128) ? nw[i] : nb[i - 6 * 128];
  if (blockIdx.y == 1) {   // zero agg1 rows [n0, n0+128)
    const float4 z = {0.f, 0.f, 0.f, 0.f};
    for (int i = tid; i < 128 * 32; i += 256) {
      const int n = n0 + (i >> 5);
      if (n < NN) *(float4*)&zb[n * HH + (i & 31) * 4] = z;
    }
  }
  __syncthreads();
  {
    const int tn = tid >> 2;
    const int cj = tid & 3;
#pragma unroll
    for (int ii = 0; ii < 2; ++ii) {
      const int n = tn + 64 * ii;
      const int gn = n0 + n;
      float xr[6];
      if (gn < NN) {
#pragma unroll
        for (int q = 0; q < 6; ++q) xr[q] = x[gn * 6 + q];
      }
#pragma unroll
      for (int i = 0; i < 4; ++i) {
        const int c = cj + 4 * i;
        bf16x8 bv = (bf16x8)0;
        if (gn < NN) {
          float4 r0, r1;
#pragma unroll
          for (int j = 0; j < 8; ++j) {
            const int k = c * 8 + j;
            float acc = wn[6 * 128 + k];
#pragma unroll
            for (int q = 0; q < 6; ++q) acc = fmaf(xr[q], wn[q * 128 + k], acc);
            if (j < 4) (&r0.x)[j] = acc; else (&r1.x)[j - 4] = acc;
            bv[j] = (short)bf16_of(acc);
          }
          if (wr_h0) {
            *(float4*)&h0[gn * HH + c * 8] = r0;
            *(float4*)&h0[gn * HH + c * 8 + 4] = r1;
          }
        }
        const int slot = ((n >> 4) * 4 + (c >> 2)) * 64 + (n & 15) + 16 * (c & 3);
        *(bf16x8*)&As[slot * 8] = bv;
      }
    }
  }
  __syncthreads();
  gemm_core(As, Wfrag, biasv, n0, bn0, PDh, PSh, tid);
}

// ---------------- layer-2 GEMM: plain h input ------------------------------
__global__ __launch_bounds__(256) void k_gemm_mfma(
    const float* __restrict__ h, const unsigned short* __restrict__ Wfrag,
    const float* __restrict__ biasv,
    unsigned short* __restrict__ PDh, unsigned short* __restrict__ PSh) {
  __shared__ unsigned short As[128 * 128];
  const int tid = threadIdx.x;
  const int n0 = blockIdx.x * 128;
  const int bn0 = blockIdx.y * 128;
  {
    const int tn = tid >> 2;
    const int cj = tid & 3;
#pragma unroll
    for (int ii = 0; ii < 2; ++ii) {
      const int n = tn + 64 * ii;
      const int gn = n0 + n;
#pragma unroll
      for (int i = 0; i < 4; ++i) {
        const int c = cj + 4 * i;
        bf16x8 bv;
        if (gn < NN) {
          const float4 p0 = *(const float4*)&h[gn * HH + c * 8];
          const float4 p1 = *(const float4*)&h[gn * HH + c * 8 + 4];
          bv[0] = (short)bf16_of(p0.x); bv[1] = (short)bf16_of(p0.y);
          bv[2] = (short)bf16_of(p0.z); bv[3] = (short)bf16_of(p0.w);
          bv[4] = (short)bf16_of(p1.x); bv[5] = (short)bf16_of(p1.y);
          bv[6] = (short)bf16_of(p1.z); bv[7] = (short)bf16_of(p1.w);
        } else {
          bv = (bf16x8)0;
        }
        const int slot = ((n >> 4) * 4 + (c >> 2)) * 64 + (n & 15) + 16 * (c & 3);
        *(bf16x8*)&As[slot * 8] = bv;
      }
    }
  }
  __syncthreads();
  gemm_core(As, Wfrag, biasv, n0, bn0, PDh, PSh, tid);
}

__global__ __launch_bounds__(1024) void k_scan(
    const int* __restrict__ deg, int* __restrict__ rowptr) {
  __shared__ int part[1024];
  const int tid = threadIdx.x;
  const int CH = (NN + 1023) / 1024;
  const int base = tid * CH;
  int s = 0;
  for (int i = 0; i < CH; ++i) {
    int n = base + i;
    if (n < NN) s += deg[n];
  }
  part[tid] = s;
  __syncthreads();
  for (int off = 1; off < 1024; off <<= 1) {
    int t = (tid >= off) ? part[tid - off] : 0;
    __syncthreads();
    part[tid] += t;
    __syncthreads();
  }
  int run = part[tid] - s;
  for (int i = 0; i < CH; ++i) {
    int n = base + i;
    if (n < NN) {
      rowptr[n] = run;
      run += deg[n];
    }
  }
}

// scatter: atomic-free; pos = rowptr[dst] + rank[e]; 8B packed metadata
__global__ __launch_bounds__(256) void k_scatter(
    const int* __restrict__ ei, const float* __restrict__ eattr,
    const int* __restrict__ rowptr, const int* __restrict__ rank,
    int2* __restrict__ emeta) {
  int e = blockIdx.x * 256 + threadIdx.x;
  if (e >= NE) return;
  const int dst = ei[NE + e];
  const int src = ei[e];
  const int bin = (int)(eattr[e] * BINSC + 0.5f);
  const int pos = rowptr[dst] + rank[e];
  emeta[pos] = make_int2(src | (dst << 16), bin << 8);
}

// -------- sorted edge kernel: PD run-boundary prefetch, XCD swizzle --------
__global__ __launch_bounds__(256) void k_edge_sorted(
    const int2* __restrict__ emeta, const unsigned short* __restrict__ LUTh,
    const unsigned short* __restrict__ PDh, const unsigned short* __restrict__ PSh,
    float* __restrict__ agg) {
  const int tid = threadIdx.x;
  const int lane = tid & 63;
  const int w = __builtin_amdgcn_readfirstlane(tid >> 6);
  const int bid = blockIdx.x;
  const int xcd = bid & 7;
  const int idx = bid >> 3;
  const int sb = ((xcd < 5) ? xcd * 391 : 5 * 391 + (xcd - 5) * 390) + idx;
  const int e0 = sb * 128 + w * 32;
  const int u4 = 4 * lane;
  float m0 = 0.f, m1 = 0.f;
  int cur = -1;
  f32x2 a0 = 0.f, a1 = 0.f;
  uint2 b[4], v[4];
  int pend_dst = (int)((unsigned)emeta[e0].x >> 16);
  uint2 pend = *(const uint2*)&PDh[(pend_dst << 8) + u4];
#pragma unroll
  for (int p = 0; p < 4; ++p) {
    const int2 md = emeta[e0 + p];
    b[p] = *(const uint2*)&PSh[((md.x & 0xffff) << 8) + u4];
    v[p] = *(const uint2*)&LUTh[md.y + u4];
  }
#pragma unroll
  for (int it = 0; it < 32; ++it) {
    const int sl = it & 3;
    const int dst = (int)((unsigned)emeta[e0 + it].x >> 16);
    if (dst != cur) {
      uint2 ad;
      if (dst == pend_dst) ad = pend;
      else ad = *(const uint2*)&PDh[(dst << 8) + u4];
      a0 = bf2_unpack(ad.x);
      a1 = bf2_unpack(ad.y);
      cur = dst;
    }
    const f32x2 bb0 = bf2_unpack(b[sl].x);
    const f32x2 bb1 = bf2_unpack(b[sl].y);
    const f32x2 w0 = bf2_unpack(v[sl].x);
    const f32x2 w1 = bf2_unpack(v[sl].y);
    if (it < 28) {
      const int2 mn = emeta[e0 + it + 4];
      b[sl] = *(const uint2*)&PSh[((mn.x & 0xffff) << 8) + u4];
      v[sl] = *(const uint2*)&LUTh[mn.y + u4];
      const int d4 = (int)((unsigned)mn.x >> 16);
      const int d3 = (int)((unsigned)emeta[e0 + it + 3].x >> 16);
      if (d4 != d3) {
        pend = *(const uint2*)&PDh[(d4 << 8) + u4];
        pend_dst = d4;
      }
    }
    const f32x2 fs0 = (a0 + bb0) + w0;
    const f32x2 fs1 = (a1 + bb1) + w1;
    const float ef0 = __builtin_amdgcn_exp2f(-fs0.x * LOG2E);
    const float ef1 = __builtin_amdgcn_exp2f(-fs1.x * LOG2E);
    const float et0 = __builtin_amdgcn_exp2f(-fabsf(fs0.y) * LOG2E);
    const float et1 = __builtin_amdgcn_exp2f(-fabsf(fs1.y) * LOG2E);
    const float sig0 = __builtin_amdgcn_rcpf(1.f + ef0);
    const float sig1 = __builtin_amdgcn_rcpf(1.f + ef1);
    const float sp0 = fmaxf(fs0.y, 0.f) + LN2 * __builtin_amdgcn_logf(1.f + et0);
    const float sp1 = fmaxf(fs1.y, 0.f) + LN2 * __builtin_amdgcn_logf(1.f + et1);
    m0 = fmaf(sig0, sp0, m0);
    m1 = fmaf(sig1, sp1, m1);
    bool fl = true;
    if (it < 31) fl = ((int)((unsigned)emeta[e0 + it + 1].x >> 16) != dst);
    if (fl) {
      atomicAdd(&agg[dst * HH + 2 * lane], m0);
      atomicAdd(&agg[dst * HH + 2 * lane + 1], m1);
      m0 = 0.f;
      m1 = 0.f;
    }
  }
}

// ------- stats stage 1: block-local reduce -> partials (NO atomics) -------
__global__ __launch_bounds__(256) void k_stats1(
    const float* __restrict__ agg, float* __restrict__ partials) {
  __shared__ float ls[8][128], ls2[8][128];
  const int tid = threadIdx.x;
  const int sub = tid >> 5;
  const int c4 = (tid & 31) * 4;
  f32x4 s = (f32x4)0.f, s2 = (f32x4)0.f;
  for (int n = blockIdx.x * 8 + sub; n < NN; n += 2048) {
    const float4 vv = *(const float4*)&agg[n * HH + c4];
    s.x += vv.x; s.y += vv.y; s.z += vv.z; s.w += vv.w;
    s2.x = fmaf(vv.x, vv.x, s2.x);
    s2.y = fmaf(vv.y, vv.y, s2.y);
    s2.z = fmaf(vv.z, vv.z, s2.z);
    s2.w = fmaf(vv.w, vv.w, s2.w);
  }
#pragma unroll
  for (int j = 0; j < 4; ++j) {
    ls[sub][c4 + j] = s[j];
    ls2[sub][c4 + j] = s2[j];
  }
  __syncthreads();
  if (tid < 128) {
    float t = 0.f, t2 = 0.f;
#pragma unroll
    for (int r = 0; r < 8; ++r) {
      t += ls[r][tid];
      t2 += ls2[r][tid];
    }
    partials[blockIdx.x * 256 + tid] = t;
    partials[blockIdx.x * 256 + 128 + tid] = t2;
  }
}

// ------- stats stage 2: reduce 256 partial blocks -> stats (plain store) ---
__global__ __launch_bounds__(256) void k_stats2(
    const float* __restrict__ partials, float* __restrict__ stats) {
  const int tid = threadIdx.x;
  float t = 0.f;
  for (int b = 0; b < 256; ++b) t += partials[b * 256 + tid];
  stats[tid] = t;
}

// ---------------- batchnorm + residual + relu (layer 1) + zero bufA --------
__global__ __launch_bounds__(256) void k_bn(
    const float* __restrict__ agg, float* __restrict__ hold,
    const float* __restrict__ stats, const float* __restrict__ g,
    const float* __restrict__ b, float* __restrict__ hnew) {
  int t = blockIdx.x * 256 + threadIdx.x;
  if (t >= NH) return;
  const int c = t & 127;
  const float inv_n = 1.f / (float)NN;
  const float mu = stats[c] * inv_n;
  const float var = stats[HH + c] * inv_n - mu * mu;
  const float rs = rsqrtf(var + 1e-5f);
  const float v = (agg[t] - mu) * rs * g[c] + b[c] + hold[t];
  hnew[t] = fmaxf(v, 0.f);
  hold[t] = 0.f;
}

// ---------------- final fc: fused BN2+residual+ReLU then h2 @ fc_w ---------
__global__ __launch_bounds__(256) void k_fc(
    const float* __restrict__ agg, const float* __restrict__ hold,
    const float* __restrict__ stats, const float* __restrict__ g,
    const float* __restrict__ bb, const float* __restrict__ w,
    const float* __restrict__ b, float* __restrict__ out) {
  __shared__ float hs[8][128];
  __shared__ float scale[128], shift[128];
  const int tid = threadIdx.x;
  const int n0 = blockIdx.x * 8;
  if (tid < 128) {
    const float inv_n = 1.f / (float)NN;
    const float mu = stats[tid] * inv_n;
    const float var = stats[128 + tid] * inv_n - mu * mu;
    const float sc = rsqrtf(var + 1e-5f) * g[tid];
    scale[tid] = sc;
    shift[tid] = bb[tid] - mu * sc;
  }
  __syncthreads();
  {
    const int nl = tid >> 5;
    const int k0 = (tid & 31) * 4;
    const int gn = n0 + nl;
    if (gn < NN) {
      const float4 av = *(const float4*)&agg[gn * HH + k0];
      const float4 ov = *(const float4*)&hold[gn * HH + k0];
#pragma unroll
      for (int jj = 0; jj < 4; ++jj) {
        const int k = k0 + jj;
        const float a = (&av.x)[jj], o = (&ov.x)[jj];
        hs[nl][k] = fmaxf(fmaf(a, scale[k], shift[k]) + o, 0.f);
      }
    }
  }
  __syncthreads();
  const int ln = tid >> 5;
  const int m = tid & 31;
  const int n = n0 + ln;
  if (n >= NN || m >= 21) return;
  float acc = b[m];
#pragma unroll 4
  for (int k = 0; k < HH; ++k) acc = fmaf(hs[ln][k], w[k * 21 + m], acc);
  out[n * 21 + m] = acc;
}

extern "C" void kernel_launch(void* const* d_in, const int* in_sizes, int n_in,
                              void* d_out, int out_size, void* d_ws, size_t ws_size,
                              hipStream_t stream) {
  const float* x      = (const float*)d_in[0];
  const float* eattr  = (const float*)d_in[1];
  const float* node_w = (const float*)d_in[2];
  const float* node_b = (const float*)d_in[3];
  const float* f1w    = (const float*)d_in[4];
  const float* f1b    = (const float*)d_in[5];
  const float* s1w    = (const float*)d_in[6];
  const float* s1b    = (const float*)d_in[7];
  const float* bn1g   = (const float*)d_in[8];
  const float* bn1b   = (const float*)d_in[9];
  const float* f2w    = (const float*)d_in[10];
  const float* f2b    = (const float*)d_in[11];
  const float* s2w    = (const float*)d_in[12];
  const float* s2b    = (const float*)d_in[13];
  const float* bn2g   = (const float*)d_in[14];
  const float* bn2b   = (const float*)d_in[15];
  const float* fcw    = (const float*)d_in[16];
  const float* fcb    = (const float*)d_in[17];
  const int*   ei     = (const int*)d_in[18];
  float* out = (float*)d_out;

  float* ws   = (float*)d_ws;
  float* bufA = ws;                          // h0, later agg2
  float* bufB = ws + NH;                     // agg1 -> h1
  unsigned short* PDh = (unsigned short*)(ws + 2 * (size_t)NH);  // [NN][256] bf16
  unsigned short* PSh = (unsigned short*)(ws + 3 * (size_t)NH);  // [NN][256] bf16
  float* stats1 = ws + 4 * (size_t)NH;       // 256
  float* stats2 = stats1 + 256;              // 256
  float* partials = stats2 + 256;            // 256*256
  int*   deg    = (int*)(partials + 256 * 256);  // NN
  int*   rowptr = deg + NN;                  // NN
  int*   rank   = rowptr + NN;               // NE
  int2*  emeta  = (int2*)(rank + NE);        // NE int2
  unsigned short* Wf1 = (unsigned short*)(emeta + NE);   // 65536 bf16
  float* bv1    = (float*)(Wf1 + 65536);     // 512
  unsigned short* Wf2 = (unsigned short*)(bv1 + 512);    // 65536 bf16
  float* bv2    = (float*)(Wf2 + 65536);     // 512
  unsigned short* lut1 = (unsigned short*)(bv2 + 512);   // (NBINS+1)*256 bf16
  unsigned short* lut2 = lut1 + (size_t)(NBINS + 1) * 256;

  const int g_edge  = NE / 128;   // 3125
  const int g_bn    = (NH + 255) / 256;
  const int g_e256  = (NE + 255) / 256;     // 1563
  const dim3 g_gemm1(1563, 5);              // y<4: gemm (x<196); y==4: hist
  const dim3 g_gemm((NN + 127) / 128, 4);
  const dim3 g_prep(1281, 2);

  // ---- prep: weight pack + LUT + deg zeroing ----
  k_prep<<<g_prep, 256, 0, stream>>>(f1w, s1w, f1b, s1b, f2w, s2w, f2b, s2b,
                                     Wf1, bv1, lut1, Wf2, bv2, lut2, deg);

  // ---- layer-1 GEMM overlapped with hist (disjoint outputs) ----
  k_gemm1<<<g_gemm1, 256, 0, stream>>>(x, node_w, node_b, Wf1, bv1, bufA,
                                       PDh, PSh, bufB, ei, deg, rank);

  // ---- scan + atomic-free scatter ----
  k_scan<<<1, 1024, 0, stream>>>(deg, rowptr);
  k_scatter<<<g_e256, 256, 0, stream>>>(ei, eattr, rowptr, rank, emeta);

  // ---- layer 1 edge + stats + bn ----
  k_edge_sorted<<<g_edge, 256, 0, stream>>>(emeta, lut1, PDh, PSh, bufB);
  k_stats1<<<256, 256, 0, stream>>>(bufB, partials);
  k_stats2<<<1, 256, 0, stream>>>(partials, stats1);
  k_bn<<<g_bn, 256, 0, stream>>>(bufB, bufA, stats1, bn1g, bn1b, bufB);

  // ---- layer 2 ----
  k_gemm_mfma<<<g_gemm, 256, 0, stream>>>(bufB, Wf2, bv2, PDh, PSh);
  k_edge_sorted<<<g_edge, 256, 0, stream>>>(emeta, lut2, PDh, PSh, bufA);
  k_stats1<<<256, 256, 0, stream>>>(bufA, partials);
  k_stats2<<<1, 256, 0, stream>>>(partials, stats2);
  k_fc<<<(NN + 7) / 8, 256, 0, stream>>>(bufA, bufB, stats2, bn2g, bn2b,
                                         fcw, fcb, out);
}